// Round 1
// baseline (84.295 us; speedup 1.0000x reference)
//
#include <hip/hip_runtime.h>

#define T_STEPS 100
#define BATCH 256
#define NIN 784
#define N0 64
#define N1 64
#define N2 10
#define CHUNK (BATCH*N0 + BATCH*N1 + BATCH*N2)   // 35328 floats per timestep in layer_spikes

// ---------------------------------------------------------------------------
// Kernel 1: I0[25600 x 64] = X[25600 x 784] @ W0^T[784 x 64] + b0
// Tile 64x64, micro-tile 4x4, BK=16 (784 = 49*16), 400 blocks x 256 threads.
// ---------------------------------------------------------------------------
__global__ __launch_bounds__(256) void gemm0_kernel(
    const float* __restrict__ X, const float* __restrict__ W0,
    const float* __restrict__ b0, float* __restrict__ I0) {
  __shared__ float As[16][68];   // [k][m], pad 68 keeps 16B alignment + spreads banks
  __shared__ float Bs[16][68];   // [k][n]

  const int tid = threadIdx.x;
  const int r0  = blockIdx.x * 64;
  const int tm  = tid >> 4;      // 0..15 -> rows tm*4..tm*4+3
  const int tn  = tid & 15;      // 0..15 -> cols tn*4..tn*4+3
  const int lm  = tid >> 2;      // 0..63 staging row
  const int lkv = tid & 3;       // 0..3  staging k-quad

  float acc[4][4];
#pragma unroll
  for (int i = 0; i < 4; ++i)
#pragma unroll
    for (int q = 0; q < 4; ++q) acc[i][q] = 0.0f;

  const float* xp = X  + (size_t)(r0 + lm) * NIN + lkv * 4;
  const float* wp = W0 + (size_t)lm * NIN + lkv * 4;

  for (int kc = 0; kc < NIN; kc += 16) {
    float4 xa = *(const float4*)(xp + kc);
    float4 wb = *(const float4*)(wp + kc);
    __syncthreads();               // WAR: previous tile fully consumed
    As[lkv*4+0][lm] = xa.x;
    As[lkv*4+1][lm] = xa.y;
    As[lkv*4+2][lm] = xa.z;
    As[lkv*4+3][lm] = xa.w;
    Bs[lkv*4+0][lm] = wb.x;
    Bs[lkv*4+1][lm] = wb.y;
    Bs[lkv*4+2][lm] = wb.z;
    Bs[lkv*4+3][lm] = wb.w;
    __syncthreads();
#pragma unroll
    for (int k = 0; k < 16; ++k) {
      float4 a = *(const float4*)&As[k][tm*4];
      float4 b = *(const float4*)&Bs[k][tn*4];
      acc[0][0] += a.x*b.x; acc[0][1] += a.x*b.y; acc[0][2] += a.x*b.z; acc[0][3] += a.x*b.w;
      acc[1][0] += a.y*b.x; acc[1][1] += a.y*b.y; acc[1][2] += a.y*b.z; acc[1][3] += a.y*b.w;
      acc[2][0] += a.z*b.x; acc[2][1] += a.z*b.y; acc[2][2] += a.z*b.z; acc[2][3] += a.z*b.w;
      acc[3][0] += a.w*b.x; acc[3][1] += a.w*b.y; acc[3][2] += a.w*b.z; acc[3][3] += a.w*b.w;
    }
  }

  float bv[4];
#pragma unroll
  for (int q = 0; q < 4; ++q) bv[q] = b0[tn*4 + q];
#pragma unroll
  for (int i = 0; i < 4; ++i) {
    const int row = r0 + tm*4 + i;
    float4 o;
    o.x = acc[i][0] + bv[0];
    o.y = acc[i][1] + bv[1];
    o.z = acc[i][2] + bv[2];
    o.w = acc[i][3] + bv[3];
    *(float4*)(I0 + (size_t)row * N0 + tn*4) = o;
  }
}

// ---------------------------------------------------------------------------
// Kernel 2: one block per batch element b. Does:
//   scan0 (LIF over t) -> GEMM1 -> scan1 -> GEMM2 -> scan2, all in LDS.
// Writes z0/z1/z2 into d_out (out_spikes + layer_spikes regions).
// ---------------------------------------------------------------------------
__global__ __launch_bounds__(256) void fused_kernel(
    const float* __restrict__ I0, const float* __restrict__ W1,
    const float* __restrict__ b1, const float* __restrict__ W2,
    const float* __restrict__ b2, float* __restrict__ out) {
  __shared__ float bufA[T_STEPS][64];   // I0 slice -> z0 -> I1 -> z1 (reused in place)
  __shared__ float sW1t[64][66];        // W1 transposed: [j][i]
  __shared__ float sW2[N2][68];         // W2 [o][j]
  __shared__ float sI2[T_STEPS][N2];    // I2 -> z2

  const int b   = blockIdx.x;
  const int tid = threadIdx.x;
  float* outSpk = out;                        // [T][B][10]
  float* laySpk = out + T_STEPS*BATCH*N2;     // [T][35328]

  // ---- stage I0 slice for this b: [T][64]
  for (int idx = tid; idx < T_STEPS*16; idx += 256) {
    int t = idx >> 4, jv = idx & 15;
    float4 v = *(const float4*)(I0 + ((size_t)t*BATCH + b) * N0 + jv*4);
    *(float4*)&bufA[t][jv*4] = v;
  }
  // ---- stage W1 transposed
  for (int idx = tid; idx < 64*16; idx += 256) {
    int i = idx >> 4, jv = idx & 15;
    float4 w = *(const float4*)(W1 + (size_t)i*64 + jv*4);
    sW1t[jv*4+0][i] = w.x;
    sW1t[jv*4+1][i] = w.y;
    sW1t[jv*4+2][i] = w.z;
    sW1t[jv*4+3][i] = w.w;
  }
  // ---- stage W2
  for (int idx = tid; idx < N2*16; idx += 256) {
    int o = idx >> 4, jv = idx & 15;
    *(float4*)&sW2[o][jv*4] = *(const float4*)(W2 + (size_t)o*64 + jv*4);
  }
  __syncthreads();

  // ---- scan0 (layer 0 LIF), in place: bufA[t][j] : I0 -> z0
  if (tid < 64) {
    float v = 0.0f;
    for (int t = 0; t < T_STEPS; ++t) {
      float icur = bufA[t][tid];
      v = v + 0.05f * ((0.0f - v) + icur);
      float z = (v > 1.0f) ? 1.0f : 0.0f;
      v -= z;
      bufA[t][tid] = z;
    }
  }
  __syncthreads();

  // ---- z0 -> layer_spikes
  for (int idx = tid; idx < T_STEPS*16; idx += 256) {
    int t = idx >> 4, jv = idx & 15;
    *(float4*)(laySpk + (size_t)t*CHUNK + b*64 + jv*4) = *(const float4*)&bufA[t][jv*4];
  }

  // ---- GEMM1: I1[t][i] = sum_j z0[t][j] * W1[i][j] + b1[i]
  // thread: i = tid&63, tq = tid>>6 owns t in [tq*25, tq*25+25)
  float acc[25];
  const int gi = tid & 63, gtq = tid >> 6;
  {
    const float bias = b1[gi];
#pragma unroll
    for (int t = 0; t < 25; ++t) acc[t] = bias;
    const int t0 = gtq * 25;
    for (int jq = 0; jq < 16; ++jq) {
      float w0 = sW1t[jq*4+0][gi];
      float w1 = sW1t[jq*4+1][gi];
      float w2 = sW1t[jq*4+2][gi];
      float w3 = sW1t[jq*4+3][gi];
#pragma unroll
      for (int t = 0; t < 25; ++t) {
        float4 z = *(const float4*)&bufA[t0 + t][jq*4];
        acc[t] += z.x*w0;
        acc[t] += z.y*w1;
        acc[t] += z.z*w2;
        acc[t] += z.w*w3;
      }
    }
  }
  __syncthreads();            // all z0 reads (GEMM1 + global write) complete
#pragma unroll
  for (int t = 0; t < 25; ++t) bufA[gtq*25 + t][gi] = acc[t];
  __syncthreads();

  // ---- scan1, in place: bufA I1 -> z1
  if (tid < 64) {
    float v = 0.0f;
    for (int t = 0; t < T_STEPS; ++t) {
      float icur = bufA[t][tid];
      v = v + 0.05f * ((0.0f - v) + icur);
      float z = (v > 1.0f) ? 1.0f : 0.0f;
      v -= z;
      bufA[t][tid] = z;
    }
  }
  __syncthreads();

  // ---- z1 -> layer_spikes
  for (int idx = tid; idx < T_STEPS*16; idx += 256) {
    int t = idx >> 4, jv = idx & 15;
    *(float4*)(laySpk + (size_t)t*CHUNK + BATCH*N0 + b*64 + jv*4) = *(const float4*)&bufA[t][jv*4];
  }

  // ---- GEMM2: I2[t][o] = sum_j z1[t][j] * W2[o][j] + b2[o]
  for (int idx = tid; idx < T_STEPS*N2; idx += 256) {
    int t = idx / N2, o = idx % N2;
    float a = b2[o];
#pragma unroll
    for (int jq = 0; jq < 16; ++jq) {
      float4 z = *(const float4*)&bufA[t][jq*4];
      float4 w = *(const float4*)&sW2[o][jq*4];
      a += z.x*w.x;
      a += z.y*w.y;
      a += z.z*w.z;
      a += z.w*w.w;
    }
    sI2[t][o] = a;
  }
  __syncthreads();

  // ---- scan2: I2 -> z2 (10 chains)
  if (tid < N2) {
    float v = 0.0f;
    for (int t = 0; t < T_STEPS; ++t) {
      float icur = sI2[t][tid];
      v = v + 0.05f * ((0.0f - v) + icur);
      float z = (v > 1.0f) ? 1.0f : 0.0f;
      v -= z;
      sI2[t][tid] = z;
    }
  }
  __syncthreads();

  // ---- z2 -> out_spikes + layer_spikes
  for (int idx = tid; idx < T_STEPS*N2; idx += 256) {
    int t = idx / N2, o = idx % N2;
    float z = sI2[t][o];
    outSpk[(size_t)t*(BATCH*N2) + b*N2 + o] = z;
    laySpk[(size_t)t*CHUNK + BATCH*(N0+N1) + b*N2 + o] = z;
  }
}

extern "C" void kernel_launch(void* const* d_in, const int* in_sizes, int n_in,
                              void* d_out, int out_size, void* d_ws, size_t ws_size,
                              hipStream_t stream) {
  const float* inp = (const float*)d_in[0];
  const float* W0  = (const float*)d_in[1];
  const float* b0  = (const float*)d_in[2];
  const float* W1  = (const float*)d_in[3];
  const float* b1  = (const float*)d_in[4];
  const float* W2  = (const float*)d_in[5];
  const float* b2  = (const float*)d_in[6];

  float* I0 = (float*)d_ws;   // 25600 * 64 * 4 = 6.55 MB scratch

  gemm0_kernel<<<dim3(400), dim3(256), 0, stream>>>(inp, W0, b0, I0);
  fused_kernel<<<dim3(256), dim3(256), 0, stream>>>(I0, W1, b1, W2, b2, (float*)d_out);
}

// Round 2
// 81.144 us; speedup vs baseline: 1.0388x; 1.0388x over previous
//
#include <hip/hip_runtime.h>

#define T_STEPS 100
#define BATCH 256
#define NIN 784
#define N0 64
#define N1 64
#define N2 10
#define CHUNK (BATCH*N0 + BATCH*N1 + BATCH*N2)   // 35328 floats per timestep in layer_spikes
#define NCHUNKS 49                               // 784 / 16
#define PLANE (25600*64)                         // one I0 partial plane (elements)

// ---------------------------------------------------------------------------
// Kernel 1: partial I0 = X[25600x784] @ W0^T[784x64], K-split over blockIdx.y.
// Pipelined: prefetch chunk c+1 before computing chunk c.
// Bias is NOT added here (fused_kernel adds it while summing partials).
// ---------------------------------------------------------------------------
__global__ __launch_bounds__(256) void gemm0_kernel(
    const float* __restrict__ X, const float* __restrict__ W0,
    float* __restrict__ I0part, int nsplit) {
  __shared__ float As[16][68];   // [k][m]
  __shared__ float Bs[16][68];   // [k][n]

  const int tid = threadIdx.x;
  const int r0  = blockIdx.x * 64;
  const int s   = blockIdx.y;
  const int tm  = tid >> 4;      // 0..15 -> rows tm*4..tm*4+3
  const int tn  = tid & 15;      // 0..15 -> cols tn*4..tn*4+3
  const int lm  = tid >> 2;      // 0..63 staging row
  const int lkv = tid & 3;       // 0..3  staging k-quad

  const int per  = NCHUNKS / nsplit;
  const int rem  = NCHUNKS % nsplit;
  const int cbeg = s * per + (s < rem ? s : rem);
  const int ccnt = per + (s < rem ? 1 : 0);

  float acc[4][4];
#pragma unroll
  for (int i = 0; i < 4; ++i)
#pragma unroll
    for (int q = 0; q < 4; ++q) acc[i][q] = 0.0f;

  const float* xp = X  + (size_t)(r0 + lm) * NIN + lkv * 4 + cbeg * 16;
  const float* wp = W0 + (size_t)lm * NIN + lkv * 4 + cbeg * 16;

  // prologue: issue chunk 0 loads
  float4 xa = *(const float4*)xp;
  float4 wb = *(const float4*)wp;

  for (int c = 0; c < ccnt; ++c) {
    __syncthreads();               // previous tile fully consumed
    As[lkv*4+0][lm] = xa.x;
    As[lkv*4+1][lm] = xa.y;
    As[lkv*4+2][lm] = xa.z;
    As[lkv*4+3][lm] = xa.w;
    Bs[lkv*4+0][lm] = wb.x;
    Bs[lkv*4+1][lm] = wb.y;
    Bs[lkv*4+2][lm] = wb.z;
    Bs[lkv*4+3][lm] = wb.w;
    // prefetch next chunk NOW — its vmcnt wait lands after a full compute
    if (c + 1 < ccnt) {
      xa = *(const float4*)(xp + (c + 1) * 16);
      wb = *(const float4*)(wp + (c + 1) * 16);
    }
    __syncthreads();
#pragma unroll
    for (int k = 0; k < 16; ++k) {
      float4 a = *(const float4*)&As[k][tm*4];
      float4 b = *(const float4*)&Bs[k][tn*4];
      acc[0][0] += a.x*b.x; acc[0][1] += a.x*b.y; acc[0][2] += a.x*b.z; acc[0][3] += a.x*b.w;
      acc[1][0] += a.y*b.x; acc[1][1] += a.y*b.y; acc[1][2] += a.y*b.z; acc[1][3] += a.y*b.w;
      acc[2][0] += a.z*b.x; acc[2][1] += a.z*b.y; acc[2][2] += a.z*b.z; acc[2][3] += a.z*b.w;
      acc[3][0] += a.w*b.x; acc[3][1] += a.w*b.y; acc[3][2] += a.w*b.z; acc[3][3] += a.w*b.w;
    }
  }

  float* op = I0part + (size_t)s * PLANE;
#pragma unroll
  for (int i = 0; i < 4; ++i) {
    const int row = r0 + tm*4 + i;
    float4 o;
    o.x = acc[i][0]; o.y = acc[i][1]; o.z = acc[i][2]; o.w = acc[i][3];
    *(float4*)(op + (size_t)row * N0 + tn*4) = o;
  }
}

// ---------------------------------------------------------------------------
// Kernel 2: one block per batch element b. Sums K-split partials (+b0) while
// staging, then scan0 -> GEMM1 -> scan1 -> GEMM2 -> scan2, all in LDS.
// ---------------------------------------------------------------------------
__global__ __launch_bounds__(256) void fused_kernel(
    const float* __restrict__ I0part, int nsplit, const float* __restrict__ b0,
    const float* __restrict__ W1, const float* __restrict__ b1,
    const float* __restrict__ W2, const float* __restrict__ b2,
    float* __restrict__ out) {
  __shared__ float bufA[T_STEPS][64];   // I0 slice -> z0 -> I1 -> z1 (reused in place)
  __shared__ float sW1t[64][66];        // W1 transposed: [j][i]
  __shared__ float sW2[N2][68];         // W2 [o][j]
  __shared__ float sI2[T_STEPS][N2];    // I2 -> z2

  const int b   = blockIdx.x;
  const int tid = threadIdx.x;
  float* outSpk = out;                        // [T][B][10]
  float* laySpk = out + T_STEPS*BATCH*N2;     // [T][35328]

  // ---- stage I0 slice for this b: sum partials + bias
  for (int idx = tid; idx < T_STEPS*16; idx += 256) {
    int t = idx >> 4, jv = idx & 15;
    size_t off = ((size_t)t*BATCH + b) * N0 + jv*4;
    float4 v = *(const float4*)(I0part + off);
    for (int s = 1; s < nsplit; ++s) {
      float4 u = *(const float4*)(I0part + (size_t)s*PLANE + off);
      v.x += u.x; v.y += u.y; v.z += u.z; v.w += u.w;
    }
    float4 bv = *(const float4*)(b0 + jv*4);
    v.x += bv.x; v.y += bv.y; v.z += bv.z; v.w += bv.w;
    *(float4*)&bufA[t][jv*4] = v;
  }
  // ---- stage W1 transposed
  for (int idx = tid; idx < 64*16; idx += 256) {
    int i = idx >> 4, jv = idx & 15;
    float4 w = *(const float4*)(W1 + (size_t)i*64 + jv*4);
    sW1t[jv*4+0][i] = w.x;
    sW1t[jv*4+1][i] = w.y;
    sW1t[jv*4+2][i] = w.z;
    sW1t[jv*4+3][i] = w.w;
  }
  // ---- stage W2
  for (int idx = tid; idx < N2*16; idx += 256) {
    int o = idx >> 4, jv = idx & 15;
    *(float4*)&sW2[o][jv*4] = *(const float4*)(W2 + (size_t)o*64 + jv*4);
  }
  __syncthreads();

  // ---- scan0 (layer 0 LIF), in place: bufA[t][j] : I0 -> z0
  if (tid < 64) {
    float v = 0.0f;
    for (int t = 0; t < T_STEPS; ++t) {
      float icur = bufA[t][tid];
      v = v + 0.05f * ((0.0f - v) + icur);
      float z = (v > 1.0f) ? 1.0f : 0.0f;
      v -= z;
      bufA[t][tid] = z;
    }
  }
  __syncthreads();

  // ---- z0 -> layer_spikes
  for (int idx = tid; idx < T_STEPS*16; idx += 256) {
    int t = idx >> 4, jv = idx & 15;
    *(float4*)(laySpk + (size_t)t*CHUNK + b*64 + jv*4) = *(const float4*)&bufA[t][jv*4];
  }

  // ---- GEMM1: I1[t][i] = sum_j z0[t][j] * W1[i][j] + b1[i]
  float acc[25];
  const int gi = tid & 63, gtq = tid >> 6;
  {
    const float bias = b1[gi];
#pragma unroll
    for (int t = 0; t < 25; ++t) acc[t] = bias;
    const int t0 = gtq * 25;
    for (int jq = 0; jq < 16; ++jq) {
      float w0 = sW1t[jq*4+0][gi];
      float w1 = sW1t[jq*4+1][gi];
      float w2 = sW1t[jq*4+2][gi];
      float w3 = sW1t[jq*4+3][gi];
#pragma unroll
      for (int t = 0; t < 25; ++t) {
        float4 z = *(const float4*)&bufA[t0 + t][jq*4];
        acc[t] += z.x*w0;
        acc[t] += z.y*w1;
        acc[t] += z.z*w2;
        acc[t] += z.w*w3;
      }
    }
  }
  __syncthreads();            // all z0 reads (GEMM1 + global write) complete
#pragma unroll
  for (int t = 0; t < 25; ++t) bufA[gtq*25 + t][gi] = acc[t];
  __syncthreads();

  // ---- scan1, in place: bufA I1 -> z1
  if (tid < 64) {
    float v = 0.0f;
    for (int t = 0; t < T_STEPS; ++t) {
      float icur = bufA[t][tid];
      v = v + 0.05f * ((0.0f - v) + icur);
      float z = (v > 1.0f) ? 1.0f : 0.0f;
      v -= z;
      bufA[t][tid] = z;
    }
  }
  __syncthreads();

  // ---- z1 -> layer_spikes
  for (int idx = tid; idx < T_STEPS*16; idx += 256) {
    int t = idx >> 4, jv = idx & 15;
    *(float4*)(laySpk + (size_t)t*CHUNK + BATCH*N0 + b*64 + jv*4) = *(const float4*)&bufA[t][jv*4];
  }

  // ---- GEMM2: I2[t][o] = sum_j z1[t][j] * W2[o][j] + b2[o]
  for (int idx = tid; idx < T_STEPS*N2; idx += 256) {
    int t = idx / N2, o = idx % N2;
    float a = b2[o];
#pragma unroll
    for (int jq = 0; jq < 16; ++jq) {
      float4 z = *(const float4*)&bufA[t][jq*4];
      float4 w = *(const float4*)&sW2[o][jq*4];
      a += z.x*w.x;
      a += z.y*w.y;
      a += z.z*w.z;
      a += z.w*w.w;
    }
    sI2[t][o] = a;
  }
  __syncthreads();

  // ---- scan2: I2 -> z2 (10 chains)
  if (tid < N2) {
    float v = 0.0f;
    for (int t = 0; t < T_STEPS; ++t) {
      float icur = sI2[t][tid];
      v = v + 0.05f * ((0.0f - v) + icur);
      float z = (v > 1.0f) ? 1.0f : 0.0f;
      v -= z;
      sI2[t][tid] = z;
    }
  }
  __syncthreads();

  // ---- z2 -> out_spikes + layer_spikes
  for (int idx = tid; idx < T_STEPS*N2; idx += 256) {
    int t = idx / N2, o = idx % N2;
    float z = sI2[t][o];
    outSpk[(size_t)t*(BATCH*N2) + b*N2 + o] = z;
    laySpk[(size_t)t*CHUNK + BATCH*(N0+N1) + b*N2 + o] = z;
  }
}

extern "C" void kernel_launch(void* const* d_in, const int* in_sizes, int n_in,
                              void* d_out, int out_size, void* d_ws, size_t ws_size,
                              hipStream_t stream) {
  const float* inp = (const float*)d_in[0];
  const float* W0  = (const float*)d_in[1];
  const float* b0  = (const float*)d_in[2];
  const float* W1  = (const float*)d_in[3];
  const float* b1  = (const float*)d_in[4];
  const float* W2  = (const float*)d_in[5];
  const float* b2  = (const float*)d_in[6];

  const size_t plane_bytes = (size_t)PLANE * sizeof(float);   // 6.55 MB
  int nsplit = 1;
  if      (ws_size >= 4 * plane_bytes) nsplit = 4;
  else if (ws_size >= 2 * plane_bytes) nsplit = 2;

  float* I0part = (float*)d_ws;

  gemm0_kernel<<<dim3(400, nsplit), dim3(256), 0, stream>>>(inp, W0, I0part, nsplit);
  fused_kernel<<<dim3(256), dim3(256), 0, stream>>>(I0part, nsplit, b0, W1, b1, W2, b2, (float*)d_out);
}